// Round 3
// baseline (514.380 us; speedup 1.0000x reference)
//
#include <hip/hip_runtime.h>
#include <hip/hip_bf16.h>

// LQR-MPC: T=50, N=12, M=4, NSC=16, NB=8192.
// 16 lanes per batch element, 4 elements per 64-thread (1-wave) block.
// Backward Riccati in LDS; gains LDS-resident (NO d_ws use - size unknown);
// forward rollout in the same wave. Runtime dtype detection (f32 vs bf16)
// from A's bit patterns; all I/O branches wave-uniformly on the flag.
// Vn = Qxx + Qxu*K exactly (K^T Qux + K^T Quu K cancels).
#define TT 50
#define NBB 8192

__device__ __forceinline__ unsigned short f2bf(float f) {
  unsigned int u = __float_as_uint(f);
  u = (u + 0x7FFFu + ((u >> 16) & 1u)) >> 16;   // RNE
  return (unsigned short)u;
}
__device__ __forceinline__ float bf2f(unsigned short h) {
  return __uint_as_float(((unsigned int)h) << 16);
}

__global__ __launch_bounds__(64) void mpc_kernel(
    const void* __restrict__ x_init, const void* __restrict__ Qm,
    const void* __restrict__ pm, const void* __restrict__ Am,
    const void* __restrict__ Bm, void* __restrict__ outv)
{
  __shared__ float sF[192];     // col-major: sF[a*12+i] = F[i][a],  F=[A|B] 12x16
  __shared__ float sFr[320];    // row-major, stride 20: sFr[i*20+a] = F[i][a]
  __shared__ float sV[4*152];   // per-elem V col-major 12x12, stride 152
  __shared__ float sQt[4*264];  // per-elem Qt col-major 16x16, stride 264
  __shared__ float sqt[4*20];   // per-elem qt (16)
  __shared__ float svv[4*20];   // per-elem v (12)
  __shared__ float sG[4*2600];  // per-elem gains: [t][col 0..12][4], col12=kff

  const int tid = threadIdx.x;
  const int c = tid & 15;
  const int e = tid >> 4;
  const int b = (int)blockIdx.x * 4 + e;

  // ---- runtime dtype detection (wave-uniform) ----
  // Read first 288 bytes of A (=144 bf16 or 72 f32: safe under both).
  // Interpret as bf16: true-f32 data has random-mantissa low halves -> wild
  // exponents; true-bf16 data (I + 0.1*randn) has all exponents in [2^-20,2^5].
  bool isf32;
  {
    const unsigned int* aw = (const unsigned int*)Am;
    int insane = 0;
    #pragma unroll 4
    for (int k = 0; k < 72; ++k) {
      const unsigned int w = aw[k];
      const unsigned short h0 = (unsigned short)(w & 0xFFFFu);
      const unsigned short h1 = (unsigned short)(w >> 16);
      const int e0 = (h0 >> 7) & 0xFF, e1 = (h1 >> 7) & 0xFF;
      insane += (((h0 & 0x7FFF) != 0) && (e0 < 107 || e0 > 132)) ? 1 : 0;
      insane += (((h1 & 0x7FFF) != 0) && (e1 < 107 || e1 > 132)) ? 1 : 0;
    }
    isf32 = (insane > 8);
  }

  const float* const xf = (const float*)x_init;
  const float* const Qf = (const float*)Qm;
  const float* const pf = (const float*)pm;
  const float* const Af = (const float*)Am;
  const float* const Bf = (const float*)Bm;
  const unsigned short* const xh = (const unsigned short*)x_init;
  const unsigned short* const Qh = (const unsigned short*)Qm;
  const unsigned short* const ph = (const unsigned short*)pm;
  const unsigned short* const Ah = (const unsigned short*)Am;
  const unsigned short* const Bh = (const unsigned short*)Bm;

  // ---- stage F ----
  for (int idx = tid; idx < 320; idx += 64) {
    const int i_ = idx / 20, a_ = idx - i_ * 20;
    float fv = 0.f;
    if (i_ < 12 && a_ < 16) {
      if (a_ < 12) fv = isf32 ? Af[i_*12 + a_] : bf2f(Ah[i_*12 + a_]);
      else         fv = isf32 ? Bf[i_*4 + (a_-12)] : bf2f(Bh[i_*4 + (a_-12)]);
    }
    sFr[idx] = fv;
  }
  for (int idx = tid; idx < 192; idx += 64) {
    const int a_ = idx / 12, i_ = idx - a_ * 12;
    float fv;
    if (a_ < 12) fv = isf32 ? Af[i_*12 + a_] : bf2f(Ah[i_*12 + a_]);
    else         fv = isf32 ? Bf[i_*4 + (a_-12)] : bf2f(Bh[i_*4 + (a_-12)]);
    sF[idx] = fv;
  }
  for (int idx = tid; idx < 4*152; idx += 64) sV[idx] = 0.f;
  for (int idx = tid; idx < 4*20; idx += 64) svv[idx] = 0.f;
  __syncthreads();

  float Fc[12];
  #pragma unroll
  for (int i = 0; i < 12; ++i) Fc[i] = sF[c*12 + i];
  const float Qd = isf32 ? Qf[b*16 + c] : bf2f(Qh[b*16 + c]);
  const float pc = isf32 ? pf[b*16 + c] : bf2f(ph[b*16 + c]);

  float* const vbase = &sV[e*152];
  float* const qtb   = &sQt[e*264];
  float* const qtsb  = &sqt[e*20];
  float* const vvb   = &svv[e*20];
  float* const gb    = &sG[e*2600];

  // ----------------- backward Riccati pass -----------------
  for (int it = 0; it < TT; ++it) {
    // W = V * F[:,c]
    float W[12];
    #pragma unroll
    for (int i = 0; i < 12; ++i) W[i] = 0.f;
    #pragma unroll
    for (int j = 0; j < 12; ++j) {
      const float4 v0 = *(const float4*)(vbase + j*12);
      const float4 v1 = *(const float4*)(vbase + j*12 + 4);
      const float4 v2 = *(const float4*)(vbase + j*12 + 8);
      const float fj = Fc[j];
      W[0]=fmaf(v0.x,fj,W[0]); W[1]=fmaf(v0.y,fj,W[1]); W[2]=fmaf(v0.z,fj,W[2]); W[3]=fmaf(v0.w,fj,W[3]);
      W[4]=fmaf(v1.x,fj,W[4]); W[5]=fmaf(v1.y,fj,W[5]); W[6]=fmaf(v1.z,fj,W[6]); W[7]=fmaf(v1.w,fj,W[7]);
      W[8]=fmaf(v2.x,fj,W[8]); W[9]=fmaf(v2.y,fj,W[9]); W[10]=fmaf(v2.z,fj,W[10]); W[11]=fmaf(v2.w,fj,W[11]);
    }
    // Qt column c: qtc[a] = F[:,a].W (+ diag Q)
    float qtc[16];
    #pragma unroll
    for (int a = 0; a < 16; ++a) {
      const float4 f0 = *(const float4*)(sF + a*12);
      const float4 f1 = *(const float4*)(sF + a*12 + 4);
      const float4 f2 = *(const float4*)(sF + a*12 + 8);
      float acc = f0.x*W[0];
      acc = fmaf(f0.y,W[1],acc); acc = fmaf(f0.z,W[2],acc); acc = fmaf(f0.w,W[3],acc);
      acc = fmaf(f1.x,W[4],acc); acc = fmaf(f1.y,W[5],acc); acc = fmaf(f1.z,W[6],acc); acc = fmaf(f1.w,W[7],acc);
      acc = fmaf(f2.x,W[8],acc); acc = fmaf(f2.y,W[9],acc); acc = fmaf(f2.z,W[10],acc); acc = fmaf(f2.w,W[11],acc);
      if (a == c) acc += Qd;
      qtc[a] = acc;
    }
    // qt[c] = p[c] + F[:,c].v
    const float4 vv0 = *(const float4*)(vvb);
    const float4 vv1 = *(const float4*)(vvb + 4);
    const float4 vv2 = *(const float4*)(vvb + 8);
    float qts = pc;
    qts = fmaf(Fc[0],vv0.x,qts); qts = fmaf(Fc[1],vv0.y,qts); qts = fmaf(Fc[2],vv0.z,qts); qts = fmaf(Fc[3],vv0.w,qts);
    qts = fmaf(Fc[4],vv1.x,qts); qts = fmaf(Fc[5],vv1.y,qts); qts = fmaf(Fc[6],vv1.z,qts); qts = fmaf(Fc[7],vv1.w,qts);
    qts = fmaf(Fc[8],vv2.x,qts); qts = fmaf(Fc[9],vv2.y,qts); qts = fmaf(Fc[10],vv2.z,qts); qts = fmaf(Fc[11],vv2.w,qts);

    *(float4*)(qtb + c*16     ) = make_float4(qtc[0],qtc[1],qtc[2],qtc[3]);
    *(float4*)(qtb + c*16 +  4) = make_float4(qtc[4],qtc[5],qtc[6],qtc[7]);
    *(float4*)(qtb + c*16 +  8) = make_float4(qtc[8],qtc[9],qtc[10],qtc[11]);
    *(float4*)(qtb + c*16 + 12) = make_float4(qtc[12],qtc[13],qtc[14],qtc[15]);
    qtsb[c] = qts;
    __syncthreads();

    // Quu (4x4) + qu broadcast from LDS
    const float4 qcol0 = *(const float4*)(qtb + 12*16 + 12);
    const float4 qcol1 = *(const float4*)(qtb + 13*16 + 12);
    const float4 qcol2 = *(const float4*)(qtb + 14*16 + 12);
    const float4 qcol3 = *(const float4*)(qtb + 15*16 + 12);
    const float4 qu    = *(const float4*)(qtsb + 12);

    // Branchless partial-pivot LU on [Quu | Qux[:,c] | qu]
    float M[4][6];
    M[0][0]=qcol0.x; M[1][0]=qcol0.y; M[2][0]=qcol0.z; M[3][0]=qcol0.w;
    M[0][1]=qcol1.x; M[1][1]=qcol1.y; M[2][1]=qcol1.z; M[3][1]=qcol1.w;
    M[0][2]=qcol2.x; M[1][2]=qcol2.y; M[2][2]=qcol2.z; M[3][2]=qcol2.w;
    M[0][3]=qcol3.x; M[1][3]=qcol3.y; M[2][3]=qcol3.z; M[3][3]=qcol3.w;
    M[0][4]=qtc[12]; M[1][4]=qtc[13]; M[2][4]=qtc[14]; M[3][4]=qtc[15];
    M[0][5]=qu.x;    M[1][5]=qu.y;    M[2][5]=qu.z;    M[3][5]=qu.w;

    #pragma unroll
    for (int k = 0; k < 4; ++k) {
      #pragma unroll
      for (int i = k+1; i < 4; ++i) {
        const bool sw = fabsf(M[i][k]) > fabsf(M[k][k]);
        #pragma unroll
        for (int j = 0; j < 6; ++j) {
          const float a_ = M[k][j], b_ = M[i][j];
          M[k][j] = sw ? b_ : a_;
          M[i][j] = sw ? a_ : b_;
        }
      }
      const float inv = 1.0f / M[k][k];
      #pragma unroll
      for (int i = k+1; i < 4; ++i) {
        const float f = M[i][k] * inv;
        #pragma unroll
        for (int j = k+1; j < 6; ++j) M[i][j] = fmaf(-f, M[k][j], M[i][j]);
      }
    }
    const float i33 = 1.0f/M[3][3], i22 = 1.0f/M[2][2], i11 = 1.0f/M[1][1], i00 = 1.0f/M[0][0];
    const float k3 = M[3][4]*i33;
    const float f3 = M[3][5]*i33;
    const float k2 = fmaf(-M[2][3],k3,M[2][4])*i22;
    const float f2v= fmaf(-M[2][3],f3,M[2][5])*i22;
    const float k1 = fmaf(-M[1][3],k3,fmaf(-M[1][2],k2,M[1][4]))*i11;
    const float f1v= fmaf(-M[1][3],f3,fmaf(-M[1][2],f2v,M[1][5]))*i11;
    const float k0 = fmaf(-M[0][3],k3,fmaf(-M[0][2],k2,fmaf(-M[0][1],k1,M[0][4])))*i00;
    const float f0v= fmaf(-M[0][3],f3,fmaf(-M[0][2],f2v,fmaf(-M[0][1],f1v,M[0][5])))*i00;
    const float4 Kc = make_float4(-k0,-k1,-k2,-k3);   // K[:,c] (valid for c<12)
    const float4 kf = make_float4(-f0v,-f1v,-f2v,-f3);

    // store gains to LDS: [t][col 0..12][4], col 12 = kff; t = TT-1-it
    if (c < 13) {
      float4 gw;
      gw.x = (c < 12) ? Kc.x : kf.x;
      gw.y = (c < 12) ? Kc.y : kf.y;
      gw.z = (c < 12) ? Kc.z : kf.z;
      gw.w = (c < 12) ? Kc.w : kf.w;
      *(float4*)(gb + (TT-1-it)*52 + c*4) = gw;
    }

    // Vn[:,c] = Qxx[:,c] + Qxu * K[:,c]
    float Vn[12];
    #pragma unroll
    for (int i = 0; i < 12; ++i) Vn[i] = qtc[i];
    #pragma unroll
    for (int u = 0; u < 4; ++u) {
      const float ku = (u==0)?Kc.x:((u==1)?Kc.y:((u==2)?Kc.z:Kc.w));
      const float4 a0 = *(const float4*)(qtb + (12+u)*16);
      const float4 a1 = *(const float4*)(qtb + (12+u)*16 + 4);
      const float4 a2 = *(const float4*)(qtb + (12+u)*16 + 8);
      Vn[0]=fmaf(a0.x,ku,Vn[0]); Vn[1]=fmaf(a0.y,ku,Vn[1]); Vn[2]=fmaf(a0.z,ku,Vn[2]); Vn[3]=fmaf(a0.w,ku,Vn[3]);
      Vn[4]=fmaf(a1.x,ku,Vn[4]); Vn[5]=fmaf(a1.y,ku,Vn[5]); Vn[6]=fmaf(a1.z,ku,Vn[6]); Vn[7]=fmaf(a1.w,ku,Vn[7]);
      Vn[8]=fmaf(a2.x,ku,Vn[8]); Vn[9]=fmaf(a2.y,ku,Vn[9]); Vn[10]=fmaf(a2.z,ku,Vn[10]); Vn[11]=fmaf(a2.w,ku,Vn[11]);
    }
    // vn[c] = qt[c] + Qxu[c,:].kff   (Qxu[c,u] = qtc[12+u] by symmetry)
    float vnc = qts;
    vnc = fmaf(qtc[12],kf.x,vnc); vnc = fmaf(qtc[13],kf.y,vnc);
    vnc = fmaf(qtc[14],kf.z,vnc); vnc = fmaf(qtc[15],kf.w,vnc);

    if (c < 12) {
      *(float4*)(vbase + c*12    ) = make_float4(Vn[0],Vn[1],Vn[2],Vn[3]);
      *(float4*)(vbase + c*12 + 4) = make_float4(Vn[4],Vn[5],Vn[6],Vn[7]);
      *(float4*)(vbase + c*12 + 8) = make_float4(Vn[8],Vn[9],Vn[10],Vn[11]);
      vvb[c] = vnc;
    }
    __syncthreads();
  }

  // ----------------- forward rollout -----------------
  float x[12];
  #pragma unroll
  for (int j = 0; j < 12; ++j)
    x[j] = isf32 ? xf[b*12 + j] : bf2f(xh[b*12 + j]);
  float xc = 0.f;
  #pragma unroll
  for (int j = 0; j < 12; ++j) if (j == c) xc = x[j];

  float* const outf = (float*)outv;
  unsigned short* const outh = (unsigned short*)outv;

  for (int t = 0; t < TT; ++t) {
    float4 g = make_float4(0.f,0.f,0.f,0.f);
    if (c < 13) g = *(const float4*)(gb + t*52 + c*4);

    // u = sum_c K[:,c]*x[c] + kff via 16-lane xor reduction
    const float s = (c < 12) ? xc : 1.0f;
    float u0 = g.x*s, u1 = g.y*s, u2 = g.z*s, u3 = g.w*s;
    #pragma unroll
    for (int m = 8; m > 0; m >>= 1) {
      u0 += __shfl_xor(u0, m, 16);
      u1 += __shfl_xor(u1, m, 16);
      u2 += __shfl_xor(u2, m, 16);
      u3 += __shfl_xor(u3, m, 16);
    }
    if (c == 0) {
      const size_t o4 = ((size_t)t*NBB + b)*4;
      if (isf32) {
        *(float4*)(outf + o4) = make_float4(u0,u1,u2,u3);
      } else {
        ushort4 us;
        us.x = f2bf(u0); us.y = f2bf(u1); us.z = f2bf(u2); us.w = f2bf(u3);
        *(ushort4*)(outh + o4) = us;
      }
    }
    // x'[c] = F[c,:] . [x;u]
    const float4 fr0 = *(const float4*)(sFr + c*20);
    const float4 fr1 = *(const float4*)(sFr + c*20 + 4);
    const float4 fr2 = *(const float4*)(sFr + c*20 + 8);
    const float4 frB = *(const float4*)(sFr + c*20 + 12);
    float xp = fr0.x*x[0];
    xp = fmaf(fr0.y,x[1],xp); xp = fmaf(fr0.z,x[2],xp); xp = fmaf(fr0.w,x[3],xp);
    xp = fmaf(fr1.x,x[4],xp); xp = fmaf(fr1.y,x[5],xp); xp = fmaf(fr1.z,x[6],xp); xp = fmaf(fr1.w,x[7],xp);
    xp = fmaf(fr2.x,x[8],xp); xp = fmaf(fr2.y,x[9],xp); xp = fmaf(fr2.z,x[10],xp); xp = fmaf(fr2.w,x[11],xp);
    xp = fmaf(frB.x,u0,xp); xp = fmaf(frB.y,u1,xp); xp = fmaf(frB.z,u2,xp); xp = fmaf(frB.w,u3,xp);
    #pragma unroll
    for (int j = 0; j < 12; ++j) {
      const float tv = __shfl(xp, j, 16);
      x[j] = tv;
      if (j == c) xc = tv;
    }
  }
}

extern "C" void kernel_launch(void* const* d_in, const int* in_sizes, int n_in,
                              void* d_out, int out_size, void* d_ws, size_t ws_size,
                              hipStream_t stream) {
  (void)in_sizes; (void)n_in; (void)out_size; (void)d_ws; (void)ws_size;
  dim3 grid(NBB / 4), block(64);
  mpc_kernel<<<grid, block, 0, stream>>>(d_in[0], d_in[1], d_in[2], d_in[3], d_in[4], d_out);
}

// Round 4
// 298.858 us; speedup vs baseline: 1.7211x; 1.7211x over previous
//
#include <hip/hip_runtime.h>
#include <hip/hip_bf16.h>

// LQR-MPC: T=50, N=12, M=4, NSC=16, NB=8192.
// 16 lanes per batch element, 4 elements per 64-thread (1-wave) block.
// Backward Riccati in LDS; gains in d_ws (f32 or bf16, host-verified size)
// or LDS fallback; forward rollout in same wave. Runtime dtype detection
// (f32 vs bf16) from A's bit patterns, wave-uniform.
// Vn = Qxx + Qxu*K exactly (K^T Qux + K^T Quu K cancels).
#define TT 50
#define NBB 8192
#define QS  20   // Qt column stride (floats), padded: start banks uniform
#define QES 328  // Qt per-element stride (floats), 328%32=8 -> elems offset 8 banks

__device__ __forceinline__ unsigned short f2bf(float f) {
  unsigned int u = __float_as_uint(f);
  u = (u + 0x7FFFu + ((u >> 16) & 1u)) >> 16;   // RNE
  return (unsigned short)u;
}
__device__ __forceinline__ float bf2f(unsigned short h) {
  return __uint_as_float(((unsigned int)h) << 16);
}

// MODE: 0 = f32 gains in d_ws, 1 = bf16 gains in d_ws, 2 = gains in LDS
template <int MODE>
__global__ __launch_bounds__(64, 4) void mpc_kernel(
    const void* __restrict__ x_init, const void* __restrict__ Qm,
    const void* __restrict__ pm, const void* __restrict__ Am,
    const void* __restrict__ Bm, void* __restrict__ outv,
    void* __restrict__ wsv)
{
  __shared__ float sF[192];       // col-major: sF[a*12+i] = F[i][a], F=[A|B] 12x16
  __shared__ float sFr[320];      // row-major, stride 20: sFr[i*20+a] = F[i][a]
  __shared__ float sV[4*152];     // per-elem V col-major 12x12, stride 152
  __shared__ float sQt[4*QES];    // per-elem Qt col-major 16 cols, col stride QS
  __shared__ float sqt[4*20];     // per-elem qt (16)
  __shared__ float svv[4*20];     // per-elem v (12)
  __shared__ float sG[(MODE == 2) ? (4*2600) : 4];  // LDS gains fallback

  const int tid = threadIdx.x;
  const int c = tid & 15;
  const int e = tid >> 4;
  const int b = (int)blockIdx.x * 4 + e;

  // ---- runtime dtype detection (wave-uniform) ----
  bool isf32;
  {
    const unsigned int* aw = (const unsigned int*)Am;
    int insane = 0;
    #pragma unroll 4
    for (int k = 0; k < 72; ++k) {
      const unsigned int w = aw[k];
      const unsigned short h0 = (unsigned short)(w & 0xFFFFu);
      const unsigned short h1 = (unsigned short)(w >> 16);
      const int e0 = (h0 >> 7) & 0xFF, e1 = (h1 >> 7) & 0xFF;
      insane += (((h0 & 0x7FFF) != 0) && (e0 < 107 || e0 > 132)) ? 1 : 0;
      insane += (((h1 & 0x7FFF) != 0) && (e1 < 107 || e1 > 132)) ? 1 : 0;
    }
    isf32 = (insane > 8);
  }

  const float* const xf = (const float*)x_init;
  const float* const Qf = (const float*)Qm;
  const float* const pf = (const float*)pm;
  const float* const Af = (const float*)Am;
  const float* const Bf = (const float*)Bm;
  const unsigned short* const xh = (const unsigned short*)x_init;
  const unsigned short* const Qh = (const unsigned short*)Qm;
  const unsigned short* const ph = (const unsigned short*)pm;
  const unsigned short* const Ah = (const unsigned short*)Am;
  const unsigned short* const Bh = (const unsigned short*)Bm;

  // ---- stage F ----
  for (int idx = tid; idx < 320; idx += 64) {
    const int i_ = idx / 20, a_ = idx - i_ * 20;
    float fv = 0.f;
    if (i_ < 12 && a_ < 16) {
      if (a_ < 12) fv = isf32 ? Af[i_*12 + a_] : bf2f(Ah[i_*12 + a_]);
      else         fv = isf32 ? Bf[i_*4 + (a_-12)] : bf2f(Bh[i_*4 + (a_-12)]);
    }
    sFr[idx] = fv;
  }
  for (int idx = tid; idx < 192; idx += 64) {
    const int a_ = idx / 12, i_ = idx - a_ * 12;
    float fv;
    if (a_ < 12) fv = isf32 ? Af[i_*12 + a_] : bf2f(Ah[i_*12 + a_]);
    else         fv = isf32 ? Bf[i_*4 + (a_-12)] : bf2f(Bh[i_*4 + (a_-12)]);
    sF[idx] = fv;
  }
  for (int idx = tid; idx < 4*152; idx += 64) sV[idx] = 0.f;
  for (int idx = tid; idx < 4*20; idx += 64) svv[idx] = 0.f;
  __syncthreads();

  float Fc[12];
  #pragma unroll
  for (int i = 0; i < 12; ++i) Fc[i] = sF[c*12 + i];
  const float Qd = isf32 ? Qf[b*16 + c] : bf2f(Qh[b*16 + c]);
  const float pc = isf32 ? pf[b*16 + c] : bf2f(ph[b*16 + c]);

  float* const vbase = &sV[e*152];
  float* const qtb   = &sQt[e*QES];
  float* const qtsb  = &sqt[e*20];
  float* const vvb   = &svv[e*20];
  float* const gb    = &sG[(MODE == 2) ? e*2600 : 0];

  float* const wsf = (float*)wsv;
  unsigned short* const wsh = (unsigned short*)wsv;

  // ----------------- backward Riccati pass -----------------
  for (int it = 0; it < TT; ++it) {
    // W = V * F[:,c]
    float W[12];
    #pragma unroll
    for (int i = 0; i < 12; ++i) W[i] = 0.f;
    #pragma unroll
    for (int j = 0; j < 12; ++j) {
      const float4 v0 = *(const float4*)(vbase + j*12);
      const float4 v1 = *(const float4*)(vbase + j*12 + 4);
      const float4 v2 = *(const float4*)(vbase + j*12 + 8);
      const float fj = Fc[j];
      W[0]=fmaf(v0.x,fj,W[0]); W[1]=fmaf(v0.y,fj,W[1]); W[2]=fmaf(v0.z,fj,W[2]); W[3]=fmaf(v0.w,fj,W[3]);
      W[4]=fmaf(v1.x,fj,W[4]); W[5]=fmaf(v1.y,fj,W[5]); W[6]=fmaf(v1.z,fj,W[6]); W[7]=fmaf(v1.w,fj,W[7]);
      W[8]=fmaf(v2.x,fj,W[8]); W[9]=fmaf(v2.y,fj,W[9]); W[10]=fmaf(v2.z,fj,W[10]); W[11]=fmaf(v2.w,fj,W[11]);
    }
    // Qt column c: qtc[a] = F[:,a].W (+ diag Q)
    float qtc[16];
    #pragma unroll
    for (int a = 0; a < 16; ++a) {
      const float4 f0 = *(const float4*)(sF + a*12);
      const float4 f1 = *(const float4*)(sF + a*12 + 4);
      const float4 f2 = *(const float4*)(sF + a*12 + 8);
      float acc = f0.x*W[0];
      acc = fmaf(f0.y,W[1],acc); acc = fmaf(f0.z,W[2],acc); acc = fmaf(f0.w,W[3],acc);
      acc = fmaf(f1.x,W[4],acc); acc = fmaf(f1.y,W[5],acc); acc = fmaf(f1.z,W[6],acc); acc = fmaf(f1.w,W[7],acc);
      acc = fmaf(f2.x,W[8],acc); acc = fmaf(f2.y,W[9],acc); acc = fmaf(f2.z,W[10],acc); acc = fmaf(f2.w,W[11],acc);
      if (a == c) acc += Qd;
      qtc[a] = acc;
    }
    // qt[c] = p[c] + F[:,c].v
    const float4 vv0 = *(const float4*)(vvb);
    const float4 vv1 = *(const float4*)(vvb + 4);
    const float4 vv2 = *(const float4*)(vvb + 8);
    float qts = pc;
    qts = fmaf(Fc[0],vv0.x,qts); qts = fmaf(Fc[1],vv0.y,qts); qts = fmaf(Fc[2],vv0.z,qts); qts = fmaf(Fc[3],vv0.w,qts);
    qts = fmaf(Fc[4],vv1.x,qts); qts = fmaf(Fc[5],vv1.y,qts); qts = fmaf(Fc[6],vv1.z,qts); qts = fmaf(Fc[7],vv1.w,qts);
    qts = fmaf(Fc[8],vv2.x,qts); qts = fmaf(Fc[9],vv2.y,qts); qts = fmaf(Fc[10],vv2.z,qts); qts = fmaf(Fc[11],vv2.w,qts);

    *(float4*)(qtb + c*QS     ) = make_float4(qtc[0],qtc[1],qtc[2],qtc[3]);
    *(float4*)(qtb + c*QS +  4) = make_float4(qtc[4],qtc[5],qtc[6],qtc[7]);
    *(float4*)(qtb + c*QS +  8) = make_float4(qtc[8],qtc[9],qtc[10],qtc[11]);
    *(float4*)(qtb + c*QS + 12) = make_float4(qtc[12],qtc[13],qtc[14],qtc[15]);
    qtsb[c] = qts;
    __syncthreads();

    // Quu (4x4) + qu broadcast from LDS
    const float4 qcol0 = *(const float4*)(qtb + 12*QS + 12);
    const float4 qcol1 = *(const float4*)(qtb + 13*QS + 12);
    const float4 qcol2 = *(const float4*)(qtb + 14*QS + 12);
    const float4 qcol3 = *(const float4*)(qtb + 15*QS + 12);
    const float4 qu    = *(const float4*)(qtsb + 12);

    // Branchless partial-pivot LU on [Quu | Qux[:,c] | qu]
    float M[4][6];
    M[0][0]=qcol0.x; M[1][0]=qcol0.y; M[2][0]=qcol0.z; M[3][0]=qcol0.w;
    M[0][1]=qcol1.x; M[1][1]=qcol1.y; M[2][1]=qcol1.z; M[3][1]=qcol1.w;
    M[0][2]=qcol2.x; M[1][2]=qcol2.y; M[2][2]=qcol2.z; M[3][2]=qcol2.w;
    M[0][3]=qcol3.x; M[1][3]=qcol3.y; M[2][3]=qcol3.z; M[3][3]=qcol3.w;
    M[0][4]=qtc[12]; M[1][4]=qtc[13]; M[2][4]=qtc[14]; M[3][4]=qtc[15];
    M[0][5]=qu.x;    M[1][5]=qu.y;    M[2][5]=qu.z;    M[3][5]=qu.w;

    #pragma unroll
    for (int k = 0; k < 4; ++k) {
      #pragma unroll
      for (int i = k+1; i < 4; ++i) {
        const bool sw = fabsf(M[i][k]) > fabsf(M[k][k]);
        #pragma unroll
        for (int j = 0; j < 6; ++j) {
          const float a_ = M[k][j], b_ = M[i][j];
          M[k][j] = sw ? b_ : a_;
          M[i][j] = sw ? a_ : b_;
        }
      }
      const float inv = __builtin_amdgcn_rcpf(M[k][k]);
      #pragma unroll
      for (int i = k+1; i < 4; ++i) {
        const float f = M[i][k] * inv;
        #pragma unroll
        for (int j = k+1; j < 6; ++j) M[i][j] = fmaf(-f, M[k][j], M[i][j]);
      }
    }
    const float i33 = __builtin_amdgcn_rcpf(M[3][3]);
    const float i22 = __builtin_amdgcn_rcpf(M[2][2]);
    const float i11 = __builtin_amdgcn_rcpf(M[1][1]);
    const float i00 = __builtin_amdgcn_rcpf(M[0][0]);
    const float k3 = M[3][4]*i33;
    const float f3 = M[3][5]*i33;
    const float k2 = fmaf(-M[2][3],k3,M[2][4])*i22;
    const float f2v= fmaf(-M[2][3],f3,M[2][5])*i22;
    const float k1 = fmaf(-M[1][3],k3,fmaf(-M[1][2],k2,M[1][4]))*i11;
    const float f1v= fmaf(-M[1][3],f3,fmaf(-M[1][2],f2v,M[1][5]))*i11;
    const float k0 = fmaf(-M[0][3],k3,fmaf(-M[0][2],k2,fmaf(-M[0][1],k1,M[0][4])))*i00;
    const float f0v= fmaf(-M[0][3],f3,fmaf(-M[0][2],f2v,fmaf(-M[0][1],f1v,M[0][5])))*i00;
    const float4 Kc = make_float4(-k0,-k1,-k2,-k3);   // K[:,c] (valid for c<12)
    const float4 kf = make_float4(-f0v,-f1v,-f2v,-f3);

    // store gains: [t][b][col 0..12][4], col 12 = kff; t = TT-1-it
    if (c < 13) {
      float4 gw;
      gw.x = (c < 12) ? Kc.x : kf.x;
      gw.y = (c < 12) ? Kc.y : kf.y;
      gw.z = (c < 12) ? Kc.z : kf.z;
      gw.w = (c < 12) ? Kc.w : kf.w;
      if (MODE == 2) {
        *(float4*)(gb + (TT-1-it)*52 + c*4) = gw;
      } else {
        const size_t off = ((size_t)(TT-1-it)*NBB + b)*52 + (size_t)c*4;
        if (MODE == 1) {
          ushort4 us;
          us.x = f2bf(gw.x); us.y = f2bf(gw.y); us.z = f2bf(gw.z); us.w = f2bf(gw.w);
          *(ushort4*)(wsh + off) = us;
        } else {
          *(float4*)(wsf + off) = gw;
        }
      }
    }

    // Vn[:,c] = Qxx[:,c] + Qxu * K[:,c]
    float Vn[12];
    #pragma unroll
    for (int i = 0; i < 12; ++i) Vn[i] = qtc[i];
    #pragma unroll
    for (int u = 0; u < 4; ++u) {
      const float ku = (u==0)?Kc.x:((u==1)?Kc.y:((u==2)?Kc.z:Kc.w));
      const float4 a0 = *(const float4*)(qtb + (12+u)*QS);
      const float4 a1 = *(const float4*)(qtb + (12+u)*QS + 4);
      const float4 a2 = *(const float4*)(qtb + (12+u)*QS + 8);
      Vn[0]=fmaf(a0.x,ku,Vn[0]); Vn[1]=fmaf(a0.y,ku,Vn[1]); Vn[2]=fmaf(a0.z,ku,Vn[2]); Vn[3]=fmaf(a0.w,ku,Vn[3]);
      Vn[4]=fmaf(a1.x,ku,Vn[4]); Vn[5]=fmaf(a1.y,ku,Vn[5]); Vn[6]=fmaf(a1.z,ku,Vn[6]); Vn[7]=fmaf(a1.w,ku,Vn[7]);
      Vn[8]=fmaf(a2.x,ku,Vn[8]); Vn[9]=fmaf(a2.y,ku,Vn[9]); Vn[10]=fmaf(a2.z,ku,Vn[10]); Vn[11]=fmaf(a2.w,ku,Vn[11]);
    }
    // vn[c] = qt[c] + Qxu[c,:].kff   (Qxu[c,u] = qtc[12+u] by symmetry)
    float vnc = qts;
    vnc = fmaf(qtc[12],kf.x,vnc); vnc = fmaf(qtc[13],kf.y,vnc);
    vnc = fmaf(qtc[14],kf.z,vnc); vnc = fmaf(qtc[15],kf.w,vnc);

    if (c < 12) {
      *(float4*)(vbase + c*12    ) = make_float4(Vn[0],Vn[1],Vn[2],Vn[3]);
      *(float4*)(vbase + c*12 + 4) = make_float4(Vn[4],Vn[5],Vn[6],Vn[7]);
      *(float4*)(vbase + c*12 + 8) = make_float4(Vn[8],Vn[9],Vn[10],Vn[11]);
      vvb[c] = vnc;
    }
    __syncthreads();
  }

  // ----------------- forward rollout -----------------
  if (MODE != 2) __threadfence();  // own stores -> own loads (same lane, same addr)

  float x[12];
  #pragma unroll
  for (int j = 0; j < 12; ++j)
    x[j] = isf32 ? xf[b*12 + j] : bf2f(xh[b*12 + j]);
  float xc = 0.f;
  #pragma unroll
  for (int j = 0; j < 12; ++j) if (j == c) xc = x[j];

  float* const outf = (float*)outv;
  unsigned short* const outh = (unsigned short*)outv;

  for (int t = 0; t < TT; ++t) {
    float4 g = make_float4(0.f,0.f,0.f,0.f);
    if (c < 13) {
      if (MODE == 2) {
        g = *(const float4*)(gb + t*52 + c*4);
      } else {
        const size_t off = ((size_t)t*NBB + b)*52 + (size_t)c*4;
        if (MODE == 1) {
          const ushort4 us = *(const ushort4*)(wsh + off);
          g = make_float4(bf2f(us.x),bf2f(us.y),bf2f(us.z),bf2f(us.w));
        } else {
          g = *(const float4*)(wsf + off);
        }
      }
    }
    // u = sum_c K[:,c]*x[c] + kff via 16-lane xor reduction
    const float s = (c < 12) ? xc : 1.0f;
    float u0 = g.x*s, u1 = g.y*s, u2 = g.z*s, u3 = g.w*s;
    #pragma unroll
    for (int m = 8; m > 0; m >>= 1) {
      u0 += __shfl_xor(u0, m, 16);
      u1 += __shfl_xor(u1, m, 16);
      u2 += __shfl_xor(u2, m, 16);
      u3 += __shfl_xor(u3, m, 16);
    }
    if (c == 0) {
      const size_t o4 = ((size_t)t*NBB + b)*4;
      if (isf32) {
        *(float4*)(outf + o4) = make_float4(u0,u1,u2,u3);
      } else {
        ushort4 us;
        us.x = f2bf(u0); us.y = f2bf(u1); us.z = f2bf(u2); us.w = f2bf(u3);
        *(ushort4*)(outh + o4) = us;
      }
    }
    // x'[c] = F[c,:] . [x;u]
    const float4 fr0 = *(const float4*)(sFr + c*20);
    const float4 fr1 = *(const float4*)(sFr + c*20 + 4);
    const float4 fr2 = *(const float4*)(sFr + c*20 + 8);
    const float4 frB = *(const float4*)(sFr + c*20 + 12);
    float xp = fr0.x*x[0];
    xp = fmaf(fr0.y,x[1],xp); xp = fmaf(fr0.z,x[2],xp); xp = fmaf(fr0.w,x[3],xp);
    xp = fmaf(fr1.x,x[4],xp); xp = fmaf(fr1.y,x[5],xp); xp = fmaf(fr1.z,x[6],xp); xp = fmaf(fr1.w,x[7],xp);
    xp = fmaf(fr2.x,x[8],xp); xp = fmaf(fr2.y,x[9],xp); xp = fmaf(fr2.z,x[10],xp); xp = fmaf(fr2.w,x[11],xp);
    xp = fmaf(frB.x,u0,xp); xp = fmaf(frB.y,u1,xp); xp = fmaf(frB.z,u2,xp); xp = fmaf(frB.w,u3,xp);
    #pragma unroll
    for (int j = 0; j < 12; ++j) {
      const float tv = __shfl(xp, j, 16);
      x[j] = tv;
      if (j == c) xc = tv;
    }
  }
}

extern "C" void kernel_launch(void* const* d_in, const int* in_sizes, int n_in,
                              void* d_out, int out_size, void* d_ws, size_t ws_size,
                              hipStream_t stream) {
  (void)in_sizes; (void)n_in; (void)out_size;
  const size_t needF = (size_t)TT * NBB * 52 * sizeof(float);          // 85.2 MB
  const size_t needH = (size_t)TT * NBB * 52 * sizeof(unsigned short); // 42.6 MB
  dim3 grid(NBB / 4), block(64);
  if (d_ws != nullptr && ws_size >= needF) {
    mpc_kernel<0><<<grid, block, 0, stream>>>(d_in[0], d_in[1], d_in[2], d_in[3], d_in[4], d_out, d_ws);
  } else if (d_ws != nullptr && ws_size >= needH) {
    mpc_kernel<1><<<grid, block, 0, stream>>>(d_in[0], d_in[1], d_in[2], d_in[3], d_in[4], d_out, d_ws);
  } else {
    mpc_kernel<2><<<grid, block, 0, stream>>>(d_in[0], d_in[1], d_in[2], d_in[3], d_in[4], d_out, d_ws);
  }
}